// Round 1
// baseline (1090.037 us; speedup 1.0000x reference)
//
#include <hip/hip_runtime.h>

typedef unsigned short u16;
typedef __bf16 bf16x8 __attribute__((ext_vector_type(8)));
typedef float f32x4 __attribute__((ext_vector_type(4)));

#define LSTR 40  // LDS row stride in u16 elems: 32 data + 8 pad (keeps 16B align, kills bank conflicts)

__device__ __forceinline__ u16 f2bf(float f) {
    union { float f; unsigned int u; } v; v.f = f;
    unsigned int u = v.u;
    u += 0x7fffu + ((u >> 16) & 1u);   // round-to-nearest-even
    return (u16)(u >> 16);
}

__device__ __forceinline__ void stage8_f32(const float* __restrict__ g, u16* __restrict__ lds) {
    float4 v0 = *(const float4*)g;
    float4 v1 = *(const float4*)(g + 4);
    lds[0] = f2bf(v0.x); lds[1] = f2bf(v0.y); lds[2] = f2bf(v0.z); lds[3] = f2bf(v0.w);
    lds[4] = f2bf(v1.x); lds[5] = f2bf(v1.y); lds[6] = f2bf(v1.z); lds[7] = f2bf(v1.w);
}

__device__ __forceinline__ void stage8_bf(const u16* __restrict__ g, u16* __restrict__ lds) {
    *(uint4*)lds = *(const uint4*)g;
}

// One 64x64 tile step over K=32, 4 waves in 2x2 arrangement, each wave 2x2 MFMA tiles.
__device__ __forceinline__ void mfma_tile(const u16* lA, const u16* lB,
                                          int wm, int wn, int quad, int m16,
                                          f32x4 (&acc)[2][2]) {
    bf16x8 a0 = *(const bf16x8*)(lA + (wm + m16) * LSTR + quad * 8);
    bf16x8 a1 = *(const bf16x8*)(lA + (wm + 16 + m16) * LSTR + quad * 8);
    bf16x8 b0 = *(const bf16x8*)(lB + (wn + m16) * LSTR + quad * 8);
    bf16x8 b1 = *(const bf16x8*)(lB + (wn + 16 + m16) * LSTR + quad * 8);
    acc[0][0] = __builtin_amdgcn_mfma_f32_16x16x32_bf16(a0, b0, acc[0][0], 0, 0, 0);
    acc[0][1] = __builtin_amdgcn_mfma_f32_16x16x32_bf16(a0, b1, acc[0][1], 0, 0, 0);
    acc[1][0] = __builtin_amdgcn_mfma_f32_16x16x32_bf16(a1, b0, acc[1][0], 0, 0, 0);
    acc[1][1] = __builtin_amdgcn_mfma_f32_16x16x32_bf16(a1, b1, acc[1][1], 0, 0, 0);
}

// ---------- 1) projection: dst = x @ W^T + b, cast bf16, head-split layout ----------
// vmode 0: dst[((b*16+h)*2048+l)*64+d]   (Q, K)
// vmode 1: dst[((b*16+h)*64+d)*2048+l]   (V transposed)
__global__ __launch_bounds__(256) void k_proj(const float* __restrict__ X,
                                              const float* __restrict__ W,
                                              const float* __restrict__ bias,
                                              u16* __restrict__ dst, int vmode) {
    __shared__ __align__(16) u16 lA[64 * LSTR];
    __shared__ __align__(16) u16 lB[64 * LSTR];
    const int t = threadIdx.x;
    const int n0 = blockIdx.x * 64, m0 = blockIdx.y * 64;
    const int lane = t & 63, wave = t >> 6;
    const int wm = (wave >> 1) * 32, wn = (wave & 1) * 32;
    const int quad = lane >> 4, m16 = lane & 15;
    const int r = t >> 2, c8 = (t & 3) * 8;
    f32x4 acc[2][2] = {};
    for (int k0 = 0; k0 < 1024; k0 += 32) {
        stage8_f32(X + (size_t)(m0 + r) * 1024 + k0 + c8, &lA[r * LSTR + c8]);
        stage8_f32(W + (size_t)(n0 + r) * 1024 + k0 + c8, &lB[r * LSTR + c8]);
        __syncthreads();
        mfma_tile(lA, lB, wm, wn, quad, m16, acc);
        __syncthreads();
    }
#pragma unroll
    for (int mi = 0; mi < 2; ++mi)
#pragma unroll
        for (int ni = 0; ni < 2; ++ni) {
            const int col = n0 + wn + ni * 16 + m16;
            const float bv = bias[col];
            const int h = col >> 6, d = col & 63;
#pragma unroll
            for (int e = 0; e < 4; ++e) {
                const int row = m0 + wm + mi * 16 + quad * 4 + e;
                const int b = row >> 11, l = row & 2047;
                const float v = acc[mi][ni][e] + bv;
                size_t idx;
                if (vmode) idx = (((size_t)(b * 16 + h)) * 64 + d) * 2048 + l;
                else       idx = (((size_t)(b * 16 + h)) * 2048 + l) * 64 + d;
                dst[idx] = f2bf(v);
            }
        }
}

// ---------- 2) scores = Q K^T * 0.125 (raw, fp32) ----------
__global__ __launch_bounds__(256) void k_scores(const u16* __restrict__ Q,
                                                const u16* __restrict__ K,
                                                float* __restrict__ attn) {
    __shared__ __align__(16) u16 lA[64 * LSTR];
    __shared__ __align__(16) u16 lB[64 * LSTR];
    const int t = threadIdx.x;
    const int bh = blockIdx.z;
    const int n0 = blockIdx.x * 64, m0 = blockIdx.y * 64;
    const int lane = t & 63, wave = t >> 6;
    const int wm = (wave >> 1) * 32, wn = (wave & 1) * 32;
    const int quad = lane >> 4, m16 = lane & 15;
    const int r = t >> 2, c8 = (t & 3) * 8;
    const u16* Qh = Q + (size_t)bh * 2048 * 64;
    const u16* Kh = K + (size_t)bh * 2048 * 64;
    f32x4 acc[2][2] = {};
    for (int k0 = 0; k0 < 64; k0 += 32) {
        stage8_bf(Qh + (size_t)(m0 + r) * 64 + k0 + c8, &lA[r * LSTR + c8]);
        stage8_bf(Kh + (size_t)(n0 + r) * 64 + k0 + c8, &lB[r * LSTR + c8]);
        __syncthreads();
        mfma_tile(lA, lB, wm, wn, quad, m16, acc);
        __syncthreads();
    }
    float* ah = attn + ((size_t)bh << 22);
#pragma unroll
    for (int mi = 0; mi < 2; ++mi)
#pragma unroll
        for (int ni = 0; ni < 2; ++ni) {
            const int col = n0 + wn + ni * 16 + m16;
#pragma unroll
            for (int e = 0; e < 4; ++e) {
                const int row = m0 + wm + mi * 16 + quad * 4 + e;
                ah[(size_t)row * 2048 + col] = acc[mi][ni][e] * 0.125f;
            }
        }
}

// ---------- 3) row softmax, in place over d_out attn region ----------
__global__ __launch_bounds__(256) void k_softmax(float* __restrict__ attn) {
    float* p = attn + (size_t)blockIdx.x * 2048;
    const int t = threadIdx.x;
    const int lane = t & 63, wave = t >> 6;
    float4 v0 = *(const float4*)(p + t * 8);
    float4 v1 = *(const float4*)(p + t * 8 + 4);
    float m = fmaxf(fmaxf(fmaxf(v0.x, v0.y), fmaxf(v0.z, v0.w)),
                    fmaxf(fmaxf(v1.x, v1.y), fmaxf(v1.z, v1.w)));
#pragma unroll
    for (int o = 32; o > 0; o >>= 1) m = fmaxf(m, __shfl_xor(m, o));
    __shared__ float redm[4], reds[4];
    if (lane == 0) redm[wave] = m;
    __syncthreads();
    m = fmaxf(fmaxf(redm[0], redm[1]), fmaxf(redm[2], redm[3]));
    float e0 = __expf(v0.x - m), e1 = __expf(v0.y - m), e2 = __expf(v0.z - m), e3 = __expf(v0.w - m);
    float e4 = __expf(v1.x - m), e5 = __expf(v1.y - m), e6 = __expf(v1.z - m), e7 = __expf(v1.w - m);
    float s = ((e0 + e1) + (e2 + e3)) + ((e4 + e5) + (e6 + e7));
#pragma unroll
    for (int o = 32; o > 0; o >>= 1) s += __shfl_xor(s, o);
    if (lane == 0) reds[wave] = s;
    __syncthreads();
    s = (reds[0] + reds[1]) + (reds[2] + reds[3]);
    const float inv = 1.0f / s;
    float4 w0 = make_float4(e0 * inv, e1 * inv, e2 * inv, e3 * inv);
    float4 w1 = make_float4(e4 * inv, e5 * inv, e6 * inv, e7 * inv);
    *(float4*)(p + t * 8) = w0;
    *(float4*)(p + t * 8 + 4) = w1;
}

// ---------- 4) ctx = attn @ V  (A fp32 staged->bf16, B = V^T bf16) ----------
__global__ __launch_bounds__(256) void k_pv(const float* __restrict__ attn,
                                            const u16* __restrict__ Vt,
                                            u16* __restrict__ ctx) {
    __shared__ __align__(16) u16 lA[64 * LSTR];
    __shared__ __align__(16) u16 lB[64 * LSTR];
    const int t = threadIdx.x;
    const int bh = blockIdx.z;
    const int m0 = blockIdx.y * 64;
    const int lane = t & 63, wave = t >> 6;
    const int wm = (wave >> 1) * 32, wn = (wave & 1) * 32;
    const int quad = lane >> 4, m16 = lane & 15;
    const int r = t >> 2, c8 = (t & 3) * 8;
    const float* Ah = attn + ((size_t)bh << 22);
    const u16* Bh = Vt + (size_t)bh * 64 * 2048;
    f32x4 acc[2][2] = {};
    for (int k0 = 0; k0 < 2048; k0 += 32) {
        stage8_f32(Ah + (size_t)(m0 + r) * 2048 + k0 + c8, &lA[r * LSTR + c8]);
        stage8_bf(Bh + (size_t)r * 2048 + k0 + c8, &lB[r * LSTR + c8]);
        __syncthreads();
        mfma_tile(lA, lB, wm, wn, quad, m16, acc);
        __syncthreads();
    }
    const int b = bh >> 4, h = bh & 15;
#pragma unroll
    for (int mi = 0; mi < 2; ++mi)
#pragma unroll
        for (int ni = 0; ni < 2; ++ni) {
            const int col = wn + ni * 16 + m16;  // 0..63 = d
#pragma unroll
            for (int e = 0; e < 4; ++e) {
                const int row = m0 + wm + mi * 16 + quad * 4 + e;  // l
                ctx[((size_t)(b * 2048 + row)) * 1024 + h * 64 + col] = f2bf(acc[mi][ni][e]);
            }
        }
}

// ---------- 5) out = ctx @ Wo^T + bo (fp32 out) ----------
__global__ __launch_bounds__(256) void k_out(const u16* __restrict__ ctx,
                                             const float* __restrict__ Wo,
                                             const float* __restrict__ bo,
                                             float* __restrict__ out) {
    __shared__ __align__(16) u16 lA[64 * LSTR];
    __shared__ __align__(16) u16 lB[64 * LSTR];
    const int t = threadIdx.x;
    const int n0 = blockIdx.x * 64, m0 = blockIdx.y * 64;
    const int lane = t & 63, wave = t >> 6;
    const int wm = (wave >> 1) * 32, wn = (wave & 1) * 32;
    const int quad = lane >> 4, m16 = lane & 15;
    const int r = t >> 2, c8 = (t & 3) * 8;
    f32x4 acc[2][2] = {};
    for (int k0 = 0; k0 < 1024; k0 += 32) {
        stage8_bf(ctx + (size_t)(m0 + r) * 1024 + k0 + c8, &lA[r * LSTR + c8]);
        stage8_f32(Wo + (size_t)(n0 + r) * 1024 + k0 + c8, &lB[r * LSTR + c8]);
        __syncthreads();
        mfma_tile(lA, lB, wm, wn, quad, m16, acc);
        __syncthreads();
    }
#pragma unroll
    for (int mi = 0; mi < 2; ++mi)
#pragma unroll
        for (int ni = 0; ni < 2; ++ni) {
            const int col = n0 + wn + ni * 16 + m16;
            const float bv = bo[col];
#pragma unroll
            for (int e = 0; e < 4; ++e) {
                const int row = m0 + wm + mi * 16 + quad * 4 + e;
                out[(size_t)row * 1024 + col] = acc[mi][ni][e] + bv;
            }
        }
}

extern "C" void kernel_launch(void* const* d_in, const int* in_sizes, int n_in,
                              void* d_out, int out_size, void* d_ws, size_t ws_size,
                              hipStream_t stream) {
    const float* x  = (const float*)d_in[0];
    const float* Wq = (const float*)d_in[1];
    const float* bq = (const float*)d_in[2];
    const float* Wk = (const float*)d_in[3];
    const float* bk = (const float*)d_in[4];
    const float* Wv = (const float*)d_in[5];
    const float* bv = (const float*)d_in[6];
    const float* Wo = (const float*)d_in[7];
    const float* bo = (const float*)d_in[8];

    float* out_f = (float*)d_out;
    float* attn  = out_f + (size_t)4096 * 1024;  // [2,16,2048,2048]

    u16* Qb = (u16*)d_ws;                        // 4,194,304 elems (8 MB)
    u16* Kb = Qb + (size_t)4194304;
    u16* Vt = Kb + (size_t)4194304;              // V transposed [b,h,d,l]
    u16* ctx = Qb;                               // reuse Q region (Q dead after scores)

    dim3 blk(256);
    k_proj<<<dim3(16, 64), blk, 0, stream>>>(x, Wq, bq, Qb, 0);
    k_proj<<<dim3(16, 64), blk, 0, stream>>>(x, Wk, bk, Kb, 0);
    k_proj<<<dim3(16, 64), blk, 0, stream>>>(x, Wv, bv, Vt, 1);
    k_scores<<<dim3(32, 32, 32), blk, 0, stream>>>(Qb, Kb, attn);
    k_softmax<<<dim3(65536), blk, 0, stream>>>(attn);
    k_pv<<<dim3(1, 32, 32), blk, 0, stream>>>(attn, Vt, ctx);
    k_out<<<dim3(16, 64), blk, 0, stream>>>(ctx, Wo, bo, out_f);
}